// Round 1
// baseline (2493.070 us; speedup 1.0000x reference)
//
#include <hip/hip_runtime.h>

// ---- problem constants ----
#define BSZ 4
#define SEQ 2048
#define DIM 1024
#define NH  16
#define HD  64
// NTOK = BSZ*SEQ = 8192

typedef float v4f __attribute__((ext_vector_type(4)));
typedef short s8v __attribute__((ext_vector_type(8)));
typedef unsigned short u16;
typedef unsigned short u16x8 __attribute__((ext_vector_type(8)));
typedef unsigned short u16x4 __attribute__((ext_vector_type(4)));

__device__ __forceinline__ u16 f2bf(float f) {
  unsigned int u = __builtin_bit_cast(unsigned int, f);
  unsigned int r = u + 0x7fffu + ((u >> 16) & 1u);  // RNE
  return (u16)(r >> 16);
}
__device__ __forceinline__ float bf2f(u16 h) {
  return __builtin_bit_cast(float, (unsigned int)h << 16);
}

// ---------------- cast x (fp32) -> bf16 ----------------
__global__ __launch_bounds__(256) void cast_bf16_kernel(const float* __restrict__ x,
                                                        u16* __restrict__ o, int n4) {
  int i = blockIdx.x * 256 + threadIdx.x;
  if (i >= n4) return;
  v4f v = reinterpret_cast<const v4f*>(x)[i];
  u16x4 r;
  #pragma unroll
  for (int c = 0; c < 4; c++) r[c] = f2bf(v[c]);
  reinterpret_cast<u16x4*>(o)[i] = r;
}

// ---------------- transpose + cast W[k][n] -> Wt[n][k] bf16 ----------------
__global__ __launch_bounds__(256) void transpose_cast_kernel(const float* __restrict__ W0,
                                                             const float* __restrict__ W1,
                                                             const float* __restrict__ W2,
                                                             const float* __restrict__ W3,
                                                             u16* __restrict__ out) {
  const float* W = blockIdx.z == 0 ? W0 : blockIdx.z == 1 ? W1 : blockIdx.z == 2 ? W2 : W3;
  u16* T = out + (size_t)blockIdx.z * DIM * DIM;
  __shared__ float tile[32][33];
  int tx = threadIdx.x & 31, ty = threadIdx.x >> 5;
  int bn = blockIdx.x * 32, bk = blockIdx.y * 32;
  #pragma unroll
  for (int r = 0; r < 4; r++) {
    int k = bk + ty + r * 8;
    tile[ty + r * 8][tx] = W[(size_t)k * DIM + bn + tx];
  }
  __syncthreads();
  #pragma unroll
  for (int r = 0; r < 4; r++) {
    int n = bn + ty + r * 8;
    T[(size_t)n * DIM + bk + tx] = f2bf(tile[tx][ty + r * 8]);
  }
}

// ---------------- bf16 MFMA GEMM: C[M,N] = A[M,K] * Bt[N,K]^T ----------------
// 128x128 tile, BK=32, 256 threads = 4 waves (2x2), each wave 64x64 (4x4 MFMA 16x16x32).
// LDS fragment-contiguous layout: chunk16B index = ((mtile*4 + quad)*16 + mlocal),
// so a lane's 8-bf16 fragment is one ds_read_b128.
template<bool OUT_BF16>
__global__ __launch_bounds__(256) void gemm_bt(const u16* __restrict__ A, const u16* __restrict__ Bt,
                                               u16* __restrict__ Cb, float* __restrict__ Cf,
                                               const float* __restrict__ bias,
                                               int M, int N, int K) {
  const int n0 = blockIdx.x * 128, m0 = blockIdx.y * 128;
  const int t = threadIdx.x;
  const int lane = t & 63, wave = t >> 6;
  const int waveM = wave >> 1, waveN = wave & 1;
  const int quad = lane >> 4, l16 = lane & 15;
  __shared__ u16 Al[4096];
  __shared__ u16 Bl[4096];

  v4f acc[4][4];
  #pragma unroll
  for (int i = 0; i < 4; i++)
    #pragma unroll
    for (int j = 0; j < 4; j++) acc[i][j] = (v4f){0.f, 0.f, 0.f, 0.f};

  // staging: thread -> row ms (0..127), k-half hs (0/1) of the 32-wide K step
  const int ms = t >> 1, hs = t & 1;
  const u16* Ap = A  + (size_t)(m0 + ms) * K + hs * 16;
  const u16* Bp = Bt + (size_t)(n0 + ms) * K + hs * 16;
  const int w0 = (((ms >> 4) * 4 + 2 * hs) * 16 + (ms & 15)) * 8;  // ushort units
  const int w1 = w0 + 128;                                         // next quad

  const int abase = waveM * 2048 + quad * 128 + l16 * 8;
  const int bbase = waveN * 2048 + quad * 128 + l16 * 8;

  for (int k0 = 0; k0 < K; k0 += 32) {
    u16x8 a0 = *(const u16x8*)(Ap + k0);
    u16x8 a1 = *(const u16x8*)(Ap + k0 + 8);
    u16x8 b0 = *(const u16x8*)(Bp + k0);
    u16x8 b1 = *(const u16x8*)(Bp + k0 + 8);
    __syncthreads();
    *(u16x8*)(Al + w0) = a0;  *(u16x8*)(Al + w1) = a1;
    *(u16x8*)(Bl + w0) = b0;  *(u16x8*)(Bl + w1) = b1;
    __syncthreads();
    s8v af[4], bf[4];
    #pragma unroll
    for (int i = 0; i < 4; i++) af[i] = *(const s8v*)(Al + abase + i * 512);
    #pragma unroll
    for (int j = 0; j < 4; j++) bf[j] = *(const s8v*)(Bl + bbase + j * 512);
    #pragma unroll
    for (int i = 0; i < 4; i++)
      #pragma unroll
      for (int j = 0; j < 4; j++)
        acc[i][j] = __builtin_amdgcn_mfma_f32_16x16x32_bf16(af[i], bf[j], acc[i][j], 0, 0, 0);
  }

  // epilogue: C/D layout col = lane&15, row = quad*4 + r  [m89-verified]
  #pragma unroll
  for (int i = 0; i < 4; i++) {
    #pragma unroll
    for (int j = 0; j < 4; j++) {
      int gn = n0 + waveN * 64 + j * 16 + l16;
      #pragma unroll
      for (int r = 0; r < 4; r++) {
        int gm = m0 + waveM * 64 + i * 16 + quad * 4 + r;
        if (OUT_BF16) {
          Cb[(size_t)gm * N + gn] = f2bf(acc[i][j][r]);
        } else {
          Cf[(size_t)gm * N + gn] = acc[i][j][r] + bias[gn];
        }
      }
    }
  }
}

// ---------------- fp32 flash attention (causal), 64x64 tiles ----------------
// block = 256 threads; lane (tq,tk) owns 4 q-rows x 4 kv-cols of scores and
// 4 q-rows x 4 d-cols of O. PV uses shuffles to gather the full kv range.
__global__ __launch_bounds__(256) void flash_attn(const u16* __restrict__ Qb,
                                                  const u16* __restrict__ Kb,
                                                  const u16* __restrict__ Vb,
                                                  u16* __restrict__ Ob) {
  const int q0 = blockIdx.x * 64;
  const int h = blockIdx.y, bb = blockIdx.z;
  const int t = threadIdx.x;
  const int lane = t & 63;
  const int tq = t >> 4, tk = t & 15;
  __shared__ float Qs[64][68];
  __shared__ float Ks[64][68];
  __shared__ float Vs[64][68];
  const size_t base = ((size_t)bb * SEQ) * DIM + h * HD;

  // stage Q tile once, folding in the 1/sqrt(HD)=0.125 scale
  {
    int r = t >> 2, dp = (t & 3) * 16;
    const u16* src = Qb + base + (size_t)(q0 + r) * DIM + dp;
    u16x8 u0 = *(const u16x8*)src;
    u16x8 u1 = *(const u16x8*)(src + 8);
    #pragma unroll
    for (int c = 0; c < 8; c++) {
      Qs[r][dp + c]     = bf2f(u0[c]) * 0.125f;
      Qs[r][dp + 8 + c] = bf2f(u1[c]) * 0.125f;
    }
  }

  float mrun[4], lrun[4], O[4][4];
  #pragma unroll
  for (int a = 0; a < 4; a++) {
    mrun[a] = -1e30f; lrun[a] = 0.f;
    #pragma unroll
    for (int c = 0; c < 4; c++) O[a][c] = 0.f;
  }

  const int ntiles = (q0 >> 6) + 1;
  for (int it = 0; it < ntiles; ++it) {
    const int kv0 = it << 6;
    __syncthreads();
    {
      int r = t >> 2, dp = (t & 3) * 16;
      const u16* ks = Kb + base + (size_t)(kv0 + r) * DIM + dp;
      const u16* vs = Vb + base + (size_t)(kv0 + r) * DIM + dp;
      u16x8 a0 = *(const u16x8*)ks, a1 = *(const u16x8*)(ks + 8);
      u16x8 b0 = *(const u16x8*)vs, b1 = *(const u16x8*)(vs + 8);
      #pragma unroll
      for (int c = 0; c < 8; c++) {
        Ks[r][dp + c]     = bf2f(a0[c]);
        Ks[r][dp + 8 + c] = bf2f(a1[c]);
        Vs[r][dp + c]     = bf2f(b0[c]);
        Vs[r][dp + 8 + c] = bf2f(b1[c]);
      }
    }
    __syncthreads();

    // scores: s[a][c] = (Q/8) . K
    float s[4][4];
    #pragma unroll
    for (int a = 0; a < 4; a++)
      #pragma unroll
      for (int c = 0; c < 4; c++) s[a][c] = 0.f;
    #pragma unroll
    for (int d = 0; d < HD; d += 4) {
      v4f qv[4], kv[4];
      #pragma unroll
      for (int a = 0; a < 4; a++) qv[a] = *(const v4f*)&Qs[tq * 4 + a][d];
      #pragma unroll
      for (int c = 0; c < 4; c++) kv[c] = *(const v4f*)&Ks[tk * 4 + c][d];
      #pragma unroll
      for (int a = 0; a < 4; a++)
        #pragma unroll
        for (int c = 0; c < 4; c++)
          s[a][c] += qv[a][0] * kv[c][0] + qv[a][1] * kv[c][1] +
                     qv[a][2] * kv[c][2] + qv[a][3] * kv[c][3];
    }

    // causal mask (only the diagonal tile needs per-element masking)
    if (kv0 == q0) {
      #pragma unroll
      for (int a = 0; a < 4; a++)
        #pragma unroll
        for (int c = 0; c < 4; c++)
          if (kv0 + tk * 4 + c > q0 + tq * 4 + a) s[a][c] = -1e30f;
    }

    // online softmax per q-row; row state replicated across the 16 lanes of a tq-group
    #pragma unroll
    for (int a = 0; a < 4; a++) {
      float mx = fmaxf(fmaxf(s[a][0], s[a][1]), fmaxf(s[a][2], s[a][3]));
      #pragma unroll
      for (int off = 1; off < 16; off <<= 1) mx = fmaxf(mx, __shfl_xor(mx, off, 64));
      float mnew = fmaxf(mrun[a], mx);
      float alpha = __expf(mrun[a] - mnew);
      mrun[a] = mnew;
      float rs = 0.f;
      #pragma unroll
      for (int c = 0; c < 4; c++) { float p = __expf(s[a][c] - mnew); s[a][c] = p; rs += p; }
      #pragma unroll
      for (int off = 1; off < 16; off <<= 1) rs += __shfl_xor(rs, off, 64);
      lrun[a] = lrun[a] * alpha + rs;
      #pragma unroll
      for (int c = 0; c < 4; c++) O[a][c] *= alpha;
    }

    // PV: gather P across the 16 lanes of the tq-group via shuffles
    for (int g = 0; g < 16; ++g) {
      v4f vv0 = *(const v4f*)&Vs[g * 4 + 0][tk * 4];
      v4f vv1 = *(const v4f*)&Vs[g * 4 + 1][tk * 4];
      v4f vv2 = *(const v4f*)&Vs[g * 4 + 2][tk * 4];
      v4f vv3 = *(const v4f*)&Vs[g * 4 + 3][tk * 4];
      int src = (lane & 48) | g;
      #pragma unroll
      for (int a = 0; a < 4; a++) {
        float p0 = __shfl(s[a][0], src, 64);
        float p1 = __shfl(s[a][1], src, 64);
        float p2 = __shfl(s[a][2], src, 64);
        float p3 = __shfl(s[a][3], src, 64);
        #pragma unroll
        for (int c = 0; c < 4; c++)
          O[a][c] += p0 * vv0[c] + p1 * vv1[c] + p2 * vv2[c] + p3 * vv3[c];
      }
    }
  }

  // finalize: O / l, write bf16 ctx in [b,s,h,hd] layout (row-major [NTOK][DIM])
  #pragma unroll
  for (int a = 0; a < 4; a++) {
    float inv = 1.f / lrun[a];
    u16x4 o;
    #pragma unroll
    for (int c = 0; c < 4; c++) o[c] = f2bf(O[a][c] * inv);
    *(u16x4*)(Ob + base + (size_t)(q0 + tq * 4 + a) * DIM + tk * 4) = o;
  }
}

// ---------------- launch ----------------
extern "C" void kernel_launch(void* const* d_in, const int* in_sizes, int n_in,
                              void* d_out, int out_size, void* d_ws, size_t ws_size,
                              hipStream_t stream) {
  (void)in_sizes; (void)n_in; (void)out_size; (void)ws_size;
  const float* x  = (const float*)d_in[0];
  const float* Wq = (const float*)d_in[1];
  const float* Wk = (const float*)d_in[2];
  const float* Wv = (const float*)d_in[3];
  const float* Wo = (const float*)d_in[4];
  const float* bo = (const float*)d_in[5];
  float* out = (float*)d_out;

  char* ws = (char*)d_ws;
  const size_t MB = 1024ull * 1024ull;
  u16* Xb = (u16*)(ws);            // 16 MB: x cast to bf16 [8192][1024]
  u16* Wt = (u16*)(ws + 16 * MB);  //  8 MB: Wq,Wk,Wv,Wo transposed bf16 [N][K]
  u16* Qb = (u16*)(ws + 24 * MB);  // 16 MB
  u16* Kb = (u16*)(ws + 40 * MB);  // 16 MB
  u16* Vb = (u16*)(ws + 56 * MB);  // 16 MB
  u16* Cb = (u16*)(ws + 72 * MB);  // 16 MB (ctx)  -> total 88 MB

  const int NTOK = BSZ * SEQ;  // 8192
  const int n4 = NTOK * DIM / 4;
  cast_bf16_kernel<<<(n4 + 255) / 256, 256, 0, stream>>>(x, Xb, n4);
  transpose_cast_kernel<<<dim3(32, 32, 4), 256, 0, stream>>>(Wq, Wk, Wv, Wo, Wt);

  dim3 gg(DIM / 128, NTOK / 128);  // (8, 64)
  gemm_bt<true><<<gg, 256, 0, stream>>>(Xb, Wt + 0ull * DIM * DIM, Qb, nullptr, nullptr, NTOK, DIM, DIM);
  gemm_bt<true><<<gg, 256, 0, stream>>>(Xb, Wt + 1ull * DIM * DIM, Kb, nullptr, nullptr, NTOK, DIM, DIM);
  gemm_bt<true><<<gg, 256, 0, stream>>>(Xb, Wt + 2ull * DIM * DIM, Vb, nullptr, nullptr, NTOK, DIM, DIM);

  flash_attn<<<dim3(SEQ / 64, NH, BSZ), 256, 0, stream>>>(Qb, Kb, Vb, Cb);

  gemm_bt<false><<<gg, 256, 0, stream>>>(Cb, Wt + 3ull * DIM * DIM, nullptr, out, bo, NTOK, DIM, DIM);
}

// Round 2
// 435.489 us; speedup vs baseline: 5.7248x; 5.7248x over previous
//
#include <hip/hip_runtime.h>

// ---- problem constants ----
#define BSZ 4
#define SEQ 2048
#define DIM 1024
#define NH  16
#define HD  64
#define QT  128   // q rows per block (flash)
#define KT  64    // kv rows per tile (flash)
#define PAD 72    // u16 row stride in flash LDS (16B-multiple, breaks pow2)

typedef float v4f __attribute__((ext_vector_type(4)));
typedef short s8v __attribute__((ext_vector_type(8)));
typedef unsigned short u16;
typedef unsigned short u16x8 __attribute__((ext_vector_type(8)));
typedef unsigned short u16x4 __attribute__((ext_vector_type(4)));

__device__ __forceinline__ u16 f2bf(float f) {
  unsigned int u = __builtin_bit_cast(unsigned int, f);
  unsigned int r = u + 0x7fffu + ((u >> 16) & 1u);  // RNE
  return (u16)(r >> 16);
}
__device__ __forceinline__ float bf2f(u16 h) {
  return __builtin_bit_cast(float, (unsigned int)h << 16);
}
__device__ __forceinline__ float fast_exp2(float x) {
#if __has_builtin(__builtin_amdgcn_exp2f)
  return __builtin_amdgcn_exp2f(x);
#else
  return exp2f(x);
#endif
}

// ---------------- cast x (fp32) -> bf16 ----------------
__global__ __launch_bounds__(256) void cast_bf16_kernel(const float* __restrict__ x,
                                                        u16* __restrict__ o, int n4) {
  int i = blockIdx.x * 256 + threadIdx.x;
  if (i >= n4) return;
  v4f v = reinterpret_cast<const v4f*>(x)[i];
  u16x4 r;
  #pragma unroll
  for (int c = 0; c < 4; c++) r[c] = f2bf(v[c]);
  reinterpret_cast<u16x4*>(o)[i] = r;
}

// ---------------- transpose + cast W[k][n] -> Wt[n][k] bf16 ----------------
__global__ __launch_bounds__(256) void transpose_cast_kernel(const float* __restrict__ W0,
                                                             const float* __restrict__ W1,
                                                             const float* __restrict__ W2,
                                                             const float* __restrict__ W3,
                                                             u16* __restrict__ out) {
  const float* W = blockIdx.z == 0 ? W0 : blockIdx.z == 1 ? W1 : blockIdx.z == 2 ? W2 : W3;
  u16* T = out + (size_t)blockIdx.z * DIM * DIM;
  __shared__ float tile[32][33];
  int tx = threadIdx.x & 31, ty = threadIdx.x >> 5;
  int bn = blockIdx.x * 32, bk = blockIdx.y * 32;
  #pragma unroll
  for (int r = 0; r < 4; r++) {
    int k = bk + ty + r * 8;
    tile[ty + r * 8][tx] = W[(size_t)k * DIM + bn + tx];
  }
  __syncthreads();
  #pragma unroll
  for (int r = 0; r < 4; r++) {
    int n = bn + ty + r * 8;
    T[(size_t)n * DIM + bk + tx] = f2bf(tile[tx][ty + r * 8]);
  }
}

// ---------------- transpose V [b][s][h][d] -> Vt [b][h][d][s] (bf16) ----------------
__global__ __launch_bounds__(256) void v_transpose(const u16* __restrict__ V,
                                                   u16* __restrict__ Vt) {
  __shared__ u16 tile[32][34];
  int t = threadIdx.x;
  int tx = t & 31, ty = t >> 5;
  int s0 = blockIdx.x * 32, c0 = blockIdx.y * 32, bb = blockIdx.z;
  #pragma unroll
  for (int r = 0; r < 4; r++)
    tile[ty + r * 8][tx] = V[((size_t)bb * SEQ + s0 + ty + r * 8) * DIM + c0 + tx];
  __syncthreads();
  int h = c0 >> 6, d0 = c0 & 63;
  #pragma unroll
  for (int r = 0; r < 4; r++) {
    int dd = ty + r * 8;
    Vt[(((size_t)bb * NH + h) * HD + d0 + dd) * SEQ + s0 + tx] = tile[tx][dd];
  }
}

// ---------------- bf16 MFMA GEMM: C[M,N] = A[M,K] * Bt[N,K]^T ----------------
template<bool OUT_BF16>
__global__ __launch_bounds__(256) void gemm_bt(const u16* __restrict__ A, const u16* __restrict__ Bt,
                                               u16* __restrict__ Cb, float* __restrict__ Cf,
                                               const float* __restrict__ bias,
                                               int M, int N, int K) {
  const int n0 = blockIdx.x * 128, m0 = blockIdx.y * 128;
  const int t = threadIdx.x;
  const int lane = t & 63, wave = t >> 6;
  const int waveM = wave >> 1, waveN = wave & 1;
  const int quad = lane >> 4, l16 = lane & 15;
  __shared__ u16 Al[4096];
  __shared__ u16 Bl[4096];

  v4f acc[4][4];
  #pragma unroll
  for (int i = 0; i < 4; i++)
    #pragma unroll
    for (int j = 0; j < 4; j++) acc[i][j] = (v4f){0.f, 0.f, 0.f, 0.f};

  const int ms = t >> 1, hs = t & 1;
  const u16* Ap = A  + (size_t)(m0 + ms) * K + hs * 16;
  const u16* Bp = Bt + (size_t)(n0 + ms) * K + hs * 16;
  const int w0 = (((ms >> 4) * 4 + 2 * hs) * 16 + (ms & 15)) * 8;
  const int w1 = w0 + 128;

  const int abase = waveM * 2048 + quad * 128 + l16 * 8;
  const int bbase = waveN * 2048 + quad * 128 + l16 * 8;

  for (int k0 = 0; k0 < K; k0 += 32) {
    u16x8 a0 = *(const u16x8*)(Ap + k0);
    u16x8 a1 = *(const u16x8*)(Ap + k0 + 8);
    u16x8 b0 = *(const u16x8*)(Bp + k0);
    u16x8 b1 = *(const u16x8*)(Bp + k0 + 8);
    __syncthreads();
    *(u16x8*)(Al + w0) = a0;  *(u16x8*)(Al + w1) = a1;
    *(u16x8*)(Bl + w0) = b0;  *(u16x8*)(Bl + w1) = b1;
    __syncthreads();
    s8v af[4], bf[4];
    #pragma unroll
    for (int i = 0; i < 4; i++) af[i] = *(const s8v*)(Al + abase + i * 512);
    #pragma unroll
    for (int j = 0; j < 4; j++) bf[j] = *(const s8v*)(Bl + bbase + j * 512);
    #pragma unroll
    for (int i = 0; i < 4; i++)
      #pragma unroll
      for (int j = 0; j < 4; j++)
        acc[i][j] = __builtin_amdgcn_mfma_f32_16x16x32_bf16(af[i], bf[j], acc[i][j], 0, 0, 0);
  }

  #pragma unroll
  for (int i = 0; i < 4; i++) {
    #pragma unroll
    for (int j = 0; j < 4; j++) {
      int gn = n0 + waveN * 64 + j * 16 + l16;
      #pragma unroll
      for (int r = 0; r < 4; r++) {
        int gm = m0 + waveM * 64 + i * 16 + quad * 4 + r;
        if (OUT_BF16) {
          Cb[(size_t)gm * N + gn] = f2bf(acc[i][j][r]);
        } else {
          Cf[(size_t)gm * N + gn] = acc[i][j][r] + bias[gn];
        }
      }
    }
  }
}

// ---------------- MFMA flash attention (causal) ----------------
// 4 waves; wave w owns q rows [q0+32w, q0+32w+32). KV tiles of 64.
// QK^T and PV both 16x16x32 bf16 MFMA; P round-trips through LDS (reuses Q buffer).
__global__ __launch_bounds__(256, 3) void flash_attn_mfma(const u16* __restrict__ Qb,
                                                          const u16* __restrict__ Kb,
                                                          const u16* __restrict__ Vtg,
                                                          u16* __restrict__ Ob) {
  const int q0 = blockIdx.x * QT;
  const int h = blockIdx.y, bb = blockIdx.z;
  const int t = threadIdx.x;
  const int lane = t & 63, w = t >> 6;
  const int quad = lane >> 4, l16 = lane & 15;

  __shared__ u16 QPs[QT * PAD];  // Q staging, then P tiles (wave-private rows)
  __shared__ u16 Ks[KT * PAD];   // K tile, row-major [kv][d]
  __shared__ u16 Vs[HD * PAD];   // V tile, transposed [d][kv]

  // stage Q, scaled by 0.125*log2(e) (softmax runs in exp2 domain)
  {
    const int r = t >> 1, c0 = (t & 1) * 32;
    const u16* src = Qb + ((size_t)bb * SEQ + q0 + r) * DIM + h * HD + c0;
    const float scq = 0.18033688011112042f;  // 1/sqrt(64) * log2(e)
    #pragma unroll
    for (int ch = 0; ch < 4; ch++) {
      u16x8 u = *(const u16x8*)(src + ch * 8);
      u16x8 o;
      #pragma unroll
      for (int j = 0; j < 8; j++) o[j] = f2bf(bf2f(u[j]) * scq);
      *(u16x8*)(QPs + r * PAD + c0 + ch * 8) = o;
    }
  }
  __syncthreads();

  // preload Q fragments into registers (QPs becomes the P buffer afterwards)
  s8v qf[2][2];
  #pragma unroll
  for (int m = 0; m < 2; m++)
    #pragma unroll
    for (int k = 0; k < 2; k++)
      qf[m][k] = *(const s8v*)(QPs + (w * 32 + m * 16 + l16) * PAD + k * 32 + quad * 8);

  v4f O[2][4];
  float mrun[2][4], lrun[2][4];
  #pragma unroll
  for (int m = 0; m < 2; m++) {
    #pragma unroll
    for (int r = 0; r < 4; r++) { mrun[m][r] = -1e30f; lrun[m][r] = 0.f; }
    #pragma unroll
    for (int n = 0; n < 4; n++) O[m][n] = (v4f){0.f, 0.f, 0.f, 0.f};
  }

  const size_t kbase = ((size_t)bb * SEQ) * DIM + h * HD;
  const size_t vbase = (((size_t)bb * NH + h) * HD) * SEQ;
  const int wq = q0 + w * 32;
  const int ntiles = q0 / KT + 2;

  for (int it = 0; it < ntiles; ++it) {
    const int kv0 = it * KT;
    __syncthreads();
    {  // cooperative staging: K row-major, Vt (already [d][s] in global) row-major
      const int r = t >> 2, c0 = (t & 3) * 16;
      const u16* ks = Kb + kbase + (size_t)(kv0 + r) * DIM + c0;
      u16x8 k0 = *(const u16x8*)ks, k1 = *(const u16x8*)(ks + 8);
      const u16* vs = Vtg + vbase + (size_t)r * SEQ + kv0 + c0;
      u16x8 v0 = *(const u16x8*)vs, v1 = *(const u16x8*)(vs + 8);
      *(u16x8*)(Ks + r * PAD + c0) = k0;
      *(u16x8*)(Ks + r * PAD + c0 + 8) = k1;
      *(u16x8*)(Vs + r * PAD + c0) = v0;
      *(u16x8*)(Vs + r * PAD + c0 + 8) = v1;
    }
    __syncthreads();

    if (kv0 > wq + 31) continue;  // tile fully masked for this wave's rows

    // ---- QK^T: sc[m][n], C-layout (col=l16, row=quad*4+r) ----
    v4f sc[2][4];
    #pragma unroll
    for (int n = 0; n < 4; n++) {
      s8v kf0 = *(const s8v*)(Ks + (n * 16 + l16) * PAD + quad * 8);
      s8v kf1 = *(const s8v*)(Ks + (n * 16 + l16) * PAD + 32 + quad * 8);
      #pragma unroll
      for (int m = 0; m < 2; m++) {
        v4f z = (v4f){0.f, 0.f, 0.f, 0.f};
        z = __builtin_amdgcn_mfma_f32_16x16x32_bf16(qf[m][0], kf0, z, 0, 0, 0);
        sc[m][n] = __builtin_amdgcn_mfma_f32_16x16x32_bf16(qf[m][1], kf1, z, 0, 0, 0);
      }
    }

    // ---- causal mask (only last two tiles can mask) ----
    if (it >= ntiles - 2) {
      #pragma unroll
      for (int m = 0; m < 2; m++) {
        const int qrow = wq + m * 16 + quad * 4;
        #pragma unroll
        for (int n = 0; n < 4; n++) {
          const int kv = kv0 + n * 16 + l16;
          #pragma unroll
          for (int r = 0; r < 4; r++)
            if (kv > qrow + r) sc[m][n][r] = -1e30f;
        }
      }
    }

    // ---- online softmax (exp2 domain); row state lives in lanes quad*4+r ----
    float al[2][4];
    #pragma unroll
    for (int m = 0; m < 2; m++) {
      #pragma unroll
      for (int r = 0; r < 4; r++) {
        float mx = fmaxf(fmaxf(sc[m][0][r], sc[m][1][r]), fmaxf(sc[m][2][r], sc[m][3][r]));
        #pragma unroll
        for (int off = 1; off < 16; off <<= 1) mx = fmaxf(mx, __shfl_xor(mx, off, 64));
        const float mnew = fmaxf(mrun[m][r], mx);
        const float a = fast_exp2(mrun[m][r] - mnew);
        mrun[m][r] = mnew;
        float rs = 0.f;
        #pragma unroll
        for (int n = 0; n < 4; n++) {
          float p = fast_exp2(sc[m][n][r] - mnew);
          sc[m][n][r] = p;
          rs += p;
        }
        #pragma unroll
        for (int off = 1; off < 16; off <<= 1) rs += __shfl_xor(rs, off, 64);
        lrun[m][r] = lrun[m][r] * a + rs;
        al[m][r] = a;
      }
    }
    #pragma unroll
    for (int m = 0; m < 2; m++)
      #pragma unroll
      for (int n = 0; n < 4; n++)
        #pragma unroll
        for (int r = 0; r < 4; r++) O[m][n][r] *= al[m][r];

    // ---- P (bf16) -> LDS, wave-private rows ----
    #pragma unroll
    for (int m = 0; m < 2; m++)
      #pragma unroll
      for (int n = 0; n < 4; n++)
        #pragma unroll
        for (int r = 0; r < 4; r++)
          QPs[(w * 32 + m * 16 + quad * 4 + r) * PAD + n * 16 + l16] = f2bf(sc[m][n][r]);

    // ---- PV: O += P * V (A-layout P, B-layout from transposed V) ----
    s8v pf[2][2];
    #pragma unroll
    for (int m = 0; m < 2; m++)
      #pragma unroll
      for (int k = 0; k < 2; k++)
        pf[m][k] = *(const s8v*)(QPs + (w * 32 + m * 16 + l16) * PAD + k * 32 + quad * 8);
    #pragma unroll
    for (int n = 0; n < 4; n++) {
      s8v vf0 = *(const s8v*)(Vs + (n * 16 + l16) * PAD + quad * 8);
      s8v vf1 = *(const s8v*)(Vs + (n * 16 + l16) * PAD + 32 + quad * 8);
      #pragma unroll
      for (int m = 0; m < 2; m++) {
        O[m][n] = __builtin_amdgcn_mfma_f32_16x16x32_bf16(pf[m][0], vf0, O[m][n], 0, 0, 0);
        O[m][n] = __builtin_amdgcn_mfma_f32_16x16x32_bf16(pf[m][1], vf1, O[m][n], 0, 0, 0);
      }
    }
  }

  // ---- epilogue: normalize, bounce through LDS for coalesced global write ----
  #pragma unroll
  for (int m = 0; m < 2; m++) {
    #pragma unroll
    for (int r = 0; r < 4; r++) {
      const float inv = 1.f / lrun[m][r];
      #pragma unroll
      for (int n = 0; n < 4; n++)
        QPs[(w * 32 + m * 16 + quad * 4 + r) * PAD + n * 16 + l16] = f2bf(O[m][n][r] * inv);
    }
  }
  __syncthreads();
  {
    const int r = t >> 1, c0 = (t & 1) * 32;
    u16* dst = Ob + ((size_t)bb * SEQ + q0 + r) * DIM + h * HD + c0;
    #pragma unroll
    for (int ch = 0; ch < 4; ch++)
      *(u16x8*)(dst + ch * 8) = *(const u16x8*)(QPs + r * PAD + c0 + ch * 8);
  }
}

// ---------------- launch ----------------
extern "C" void kernel_launch(void* const* d_in, const int* in_sizes, int n_in,
                              void* d_out, int out_size, void* d_ws, size_t ws_size,
                              hipStream_t stream) {
  (void)in_sizes; (void)n_in; (void)out_size; (void)ws_size;
  const float* x  = (const float*)d_in[0];
  const float* Wq = (const float*)d_in[1];
  const float* Wk = (const float*)d_in[2];
  const float* Wv = (const float*)d_in[3];
  const float* Wo = (const float*)d_in[4];
  const float* bo = (const float*)d_in[5];
  float* out = (float*)d_out;

  char* ws = (char*)d_ws;
  const size_t MB = 1024ull * 1024ull;
  u16* Xb  = (u16*)(ws);             // 16 MB
  u16* Wt  = (u16*)(ws + 16 * MB);   //  8 MB
  u16* Qb  = (u16*)(ws + 24 * MB);   // 16 MB
  u16* Kb  = (u16*)(ws + 40 * MB);   // 16 MB
  u16* Vb  = (u16*)(ws + 56 * MB);   // 16 MB
  u16* Cb  = (u16*)(ws + 72 * MB);   // 16 MB (ctx)
  u16* Vtg = (u16*)(ws + 88 * MB);   // 16 MB (V transposed per head) -> 104 MB

  const int NTOK = BSZ * SEQ;  // 8192
  const int n4 = NTOK * DIM / 4;
  cast_bf16_kernel<<<(n4 + 255) / 256, 256, 0, stream>>>(x, Xb, n4);
  transpose_cast_kernel<<<dim3(32, 32, 4), 256, 0, stream>>>(Wq, Wk, Wv, Wo, Wt);

  dim3 gg(DIM / 128, NTOK / 128);  // (8, 64)
  gemm_bt<true><<<gg, 256, 0, stream>>>(Xb, Wt + 0ull * DIM * DIM, Qb, nullptr, nullptr, NTOK, DIM, DIM);
  gemm_bt<true><<<gg, 256, 0, stream>>>(Xb, Wt + 1ull * DIM * DIM, Kb, nullptr, nullptr, NTOK, DIM, DIM);
  gemm_bt<true><<<gg, 256, 0, stream>>>(Xb, Wt + 2ull * DIM * DIM, Vb, nullptr, nullptr, NTOK, DIM, DIM);

  v_transpose<<<dim3(SEQ / 32, DIM / 32, BSZ), 256, 0, stream>>>(Vb, Vtg);

  flash_attn_mfma<<<dim3(SEQ / QT, NH, BSZ), 256, 0, stream>>>(Qb, Kb, Vtg, Cb);

  gemm_bt<false><<<gg, 256, 0, stream>>>(Cb, Wt + 3ull * DIM * DIM, nullptr, out, bo, NTOK, DIM, DIM);
}

// Round 3
// 316.668 us; speedup vs baseline: 7.8728x; 1.3752x over previous
//
#include <hip/hip_runtime.h>

// ---- problem constants ----
#define BSZ 4
#define SEQ 2048
#define DIM 1024
#define NH  16
#define HD  64
#define QT  128   // q rows per block pass (flash)
#define KT  64    // kv rows per tile (flash)
#define PAD 72    // u16 row stride in flash LDS

typedef float v4f __attribute__((ext_vector_type(4)));
typedef short s8v __attribute__((ext_vector_type(8)));
typedef unsigned short u16;
typedef unsigned short u16x8 __attribute__((ext_vector_type(8)));
typedef unsigned short u16x4 __attribute__((ext_vector_type(4)));

__device__ __forceinline__ u16 f2bf(float f) {
  unsigned int u = __builtin_bit_cast(unsigned int, f);
  unsigned int r = u + 0x7fffu + ((u >> 16) & 1u);  // RNE
  return (u16)(r >> 16);
}
__device__ __forceinline__ float bf2f(u16 h) {
  return __builtin_bit_cast(float, (unsigned int)h << 16);
}
__device__ __forceinline__ float fast_exp2(float x) {
#if __has_builtin(__builtin_amdgcn_exp2f)
  return __builtin_amdgcn_exp2f(x);
#else
  return exp2f(x);
#endif
}
// async global->LDS, 16B per lane; lds ptr must be wave-uniform (HW adds lane*16)
__device__ __forceinline__ void gll16(const u16* g, u16* l) {
  __builtin_amdgcn_global_load_lds((const __attribute__((address_space(1))) void*)g,
                                   (__attribute__((address_space(3))) void*)l, 16, 0, 0);
}

// ---------------- cast x (fp32) -> bf16 ----------------
__global__ __launch_bounds__(256) void cast_bf16_kernel(const float* __restrict__ x,
                                                        u16* __restrict__ o, int n4) {
  int i = blockIdx.x * 256 + threadIdx.x;
  if (i >= n4) return;
  v4f v = reinterpret_cast<const v4f*>(x)[i];
  u16x4 r;
  #pragma unroll
  for (int c = 0; c < 4; c++) r[c] = f2bf(v[c]);
  reinterpret_cast<u16x4*>(o)[i] = r;
}

// ---------------- transpose + cast W[k][n] -> Wt[n][k] bf16 ----------------
__global__ __launch_bounds__(256) void transpose_cast_kernel(const float* __restrict__ W0,
                                                             const float* __restrict__ W1,
                                                             const float* __restrict__ W2,
                                                             const float* __restrict__ W3,
                                                             u16* __restrict__ out) {
  const float* W = blockIdx.z == 0 ? W0 : blockIdx.z == 1 ? W1 : blockIdx.z == 2 ? W2 : W3;
  u16* T = out + (size_t)blockIdx.z * DIM * DIM;
  __shared__ float tile[32][33];
  int tx = threadIdx.x & 31, ty = threadIdx.x >> 5;
  int bn = blockIdx.x * 32, bk = blockIdx.y * 32;
  #pragma unroll
  for (int r = 0; r < 4; r++) {
    int k = bk + ty + r * 8;
    tile[ty + r * 8][tx] = W[(size_t)k * DIM + bn + tx];
  }
  __syncthreads();
  #pragma unroll
  for (int r = 0; r < 4; r++) {
    int n = bn + ty + r * 8;
    T[(size_t)n * DIM + bk + tx] = f2bf(tile[tx][ty + r * 8]);
  }
}

// ======== shared GEMM core pieces (128x128 tile, BK=32, m97-style async staging) ========
// LDS chunk layout (16B chunks): chunk = (m>>4)*64 + kk*16 + (m&15), kk = 8-u16 k-chunk.
// Staging: wave w, inst p: lane L -> global row (w*2+p)*16 + (L&15), k-chunk L>>4,
// LDS chunk (w*2+p)*64 + L  (contiguous in lane order -> global_load_lds OK).

#define GEMM_PROLOGUE()                                                          \
  const int t = threadIdx.x;                                                     \
  const int lane = t & 63, w = t >> 6;                                           \
  const int waveM = w >> 1, waveN = w & 1;                                       \
  const int quad = lane >> 4, l16 = lane & 15;                                   \
  __shared__ u16 Al[4096];                                                       \
  __shared__ u16 Bl[4096];                                                       \
  v4f acc[4][4];                                                                 \
  _Pragma("unroll") for (int i = 0; i < 4; i++)                                  \
    _Pragma("unroll") for (int j = 0; j < 4; j++)                                \
      acc[i][j] = (v4f){0.f, 0.f, 0.f, 0.f};                                     \
  const int sR = lane & 15, sC = lane >> 4;                                      \
  const u16* Ag0 = A  + (size_t)(m0 + (w * 2 + 0) * 16 + sR) * DIM + sC * 8;     \
  const u16* Ag1 = A  + (size_t)(m0 + (w * 2 + 1) * 16 + sR) * DIM + sC * 8;     \
  const u16* Bg0 = Bt + (size_t)(n0 + (w * 2 + 0) * 16 + sR) * DIM + sC * 8;     \
  const u16* Bg1 = Bt + (size_t)(n0 + (w * 2 + 1) * 16 + sR) * DIM + sC * 8;     \
  u16* Al0 = Al + (w * 2 + 0) * 512;                                             \
  u16* Al1 = Al + (w * 2 + 1) * 512;                                             \
  u16* Bl0 = Bl + (w * 2 + 0) * 512;                                             \
  u16* Bl1 = Bl + (w * 2 + 1) * 512;                                             \
  const int abase = waveM * 2048 + quad * 128 + l16 * 8;                         \
  const int bbase = waveN * 2048 + quad * 128 + l16 * 8;                         \
  for (int k0 = 0; k0 < DIM; k0 += 32) {                                         \
    __syncthreads();                                                             \
    gll16(Ag0 + k0, Al0); gll16(Ag1 + k0, Al1);                                  \
    gll16(Bg0 + k0, Bl0); gll16(Bg1 + k0, Bl1);                                  \
    __syncthreads();                                                             \
    s8v af[4], bfv[4];                                                           \
    _Pragma("unroll") for (int i = 0; i < 4; i++)                                \
      af[i] = *(const s8v*)(Al + abase + i * 512);                               \
    _Pragma("unroll") for (int j = 0; j < 4; j++)                                \
      bfv[j] = *(const s8v*)(Bl + bbase + j * 512);                              \
    _Pragma("unroll") for (int i = 0; i < 4; i++)                                \
      _Pragma("unroll") for (int j = 0; j < 4; j++)                              \
        acc[i][j] = __builtin_amdgcn_mfma_f32_16x16x32_bf16(af[i], bfv[j],       \
                                                            acc[i][j], 0, 0, 0); \
  }

// ---------------- fused QKV GEMM; z=0 -> Q, z=1 -> K, z=2 -> V written transposed ----------------
__global__ __launch_bounds__(256) void gemm_qkv(const u16* __restrict__ A, const u16* __restrict__ Wt,
                                                u16* __restrict__ Qb, u16* __restrict__ Kb,
                                                u16* __restrict__ Vtg) {
  const int z = blockIdx.z;
  const u16* Bt = Wt + (size_t)z * DIM * DIM;
  const int n0 = blockIdx.x * 128, m0 = blockIdx.y * 128;
  GEMM_PROLOGUE()
  if (z == 2) {
    // write V transposed: Vtg[((b*NH+h)*HD+d)*SEQ + s], s = token index
    #pragma unroll
    for (int i = 0; i < 4; i++) {
      #pragma unroll
      for (int j = 0; j < 4; j++) {
        int gm0 = m0 + waveM * 64 + i * 16 + quad * 4;
        int gn = n0 + waveN * 64 + j * 16 + l16;
        int b = gm0 >> 11, s0 = gm0 & (SEQ - 1), hh = gn >> 6, d = gn & (HD - 1);
        u16x4 o;
        #pragma unroll
        for (int r = 0; r < 4; r++) o[r] = f2bf(acc[i][j][r]);
        *(u16x4*)(Vtg + ((size_t)(b * NH + hh) * HD + d) * SEQ + s0) = o;
      }
    }
  } else {
    u16* C = (z == 0) ? Qb : Kb;
    #pragma unroll
    for (int i = 0; i < 4; i++) {
      #pragma unroll
      for (int j = 0; j < 4; j++) {
        int gn = n0 + waveN * 64 + j * 16 + l16;
        #pragma unroll
        for (int r = 0; r < 4; r++) {
          int gm = m0 + waveM * 64 + i * 16 + quad * 4 + r;
          C[(size_t)gm * DIM + gn] = f2bf(acc[i][j][r]);
        }
      }
    }
  }
}

// ---------------- projection GEMM: out = ctx * Wo^T + bias (fp32 out) ----------------
__global__ __launch_bounds__(256) void gemm_proj(const u16* __restrict__ A, const u16* __restrict__ Bt,
                                                 float* __restrict__ Cf, const float* __restrict__ bias) {
  const int n0 = blockIdx.x * 128, m0 = blockIdx.y * 128;
  GEMM_PROLOGUE()
  #pragma unroll
  for (int i = 0; i < 4; i++) {
    #pragma unroll
    for (int j = 0; j < 4; j++) {
      int gn = n0 + waveN * 64 + j * 16 + l16;
      float bv = bias[gn];
      #pragma unroll
      for (int r = 0; r < 4; r++) {
        int gm = m0 + waveM * 64 + i * 16 + quad * 4 + r;
        Cf[(size_t)gm * DIM + gn] = acc[i][j][r] + bv;
      }
    }
  }
}

// ---------------- MFMA flash attention (causal), transposed scores ----------------
// S^T = K*Q^T: D row = kv (via permuted K rows), col = q. Softmax reduces over kv:
// 16 in-register values + 2 shfl_xor. P^T registers are directly the PV B-fragment
// (row permutation pi(mi,quad,r) = (mi&1)*32 + quad*8 + (mi>>1)*4 + r at K staging).
// O^T[d][q] = Vt * P^T accumulated in C-layout. Causal balance: block px does
// q-tiles {px, 15-px} -> uniform 34 KV-tiles per block, 512 blocks = 2/CU.
__global__ __launch_bounds__(256, 2) void flash_attn_mfma(const u16* __restrict__ Qb,
                                                          const u16* __restrict__ Kb,
                                                          const u16* __restrict__ Vtg,
                                                          u16* __restrict__ Ob) {
  const int px = blockIdx.x, h = blockIdx.y, bb = blockIdx.z;
  const int t = threadIdx.x;
  const int lane = t & 63, w = t >> 6;
  const int quad = lane >> 4, l16 = lane & 15;

  __shared__ u16 QPs[QT * PAD];  // Q staging, then O^T epilogue bounce
  __shared__ u16 Ks[KT * PAD];   // K tile, rows permuted by pi^-1
  __shared__ u16 Vs[HD * PAD];   // V tile, [d][kv]

  const size_t qkbase = (size_t)bb * SEQ * DIM + h * HD;
  const size_t vbase = ((size_t)bb * NH + h) * (size_t)HD * SEQ;

  // staging thread->row/col mapping (fixed across tiles)
  const int vrow = t >> 2, scol = (t & 3) * 16;
  // LDS row for global kv row vrow:  s(v) = ((v>>5) + 2*((v>>2)&1))*16 + ((v>>3)&3)*4 + (v&3)
  const int krow = ((vrow >> 5) + 2 * ((vrow >> 2) & 1)) * 16 + ((vrow >> 3) & 3) * 4 + (vrow & 3);

  for (int pass = 0; pass < 2; pass++) {
    const int qi = (pass == 0) ? px : (SEQ / QT - 1 - px);
    const int q0 = qi * QT;
    const int wq = q0 + w * 32;
    const int ntiles = 2 * qi + 2;

    __syncthreads();  // QPs free (previous pass epilogue complete)

    // stage Q scaled by 1/sqrt(HD) * log2(e)  (softmax in exp2 domain)
    {
      const int r = t >> 1, c0 = (t & 1) * 32;
      const u16* src = Qb + qkbase + (size_t)(q0 + r) * DIM + c0;
      const float scq = 0.18033688011112042f;
      #pragma unroll
      for (int ch = 0; ch < 4; ch++) {
        u16x8 u = *(const u16x8*)(src + ch * 8);
        u16x8 o;
        #pragma unroll
        for (int j = 0; j < 8; j++) o[j] = f2bf(bf2f(u[j]) * scq);
        *(u16x8*)(QPs + r * PAD + c0 + ch * 8) = o;
      }
    }
    __syncthreads();

    // Q B-fragments: B[n=q][k=d]
    s8v qf[2][2];
    #pragma unroll
    for (int ni = 0; ni < 2; ni++)
      #pragma unroll
      for (int kc = 0; kc < 2; kc++)
        qf[ni][kc] = *(const s8v*)(QPs + (w * 32 + ni * 16 + l16) * PAD + kc * 32 + quad * 8);

    // preload KV tile 0 into registers
    u16x8 kr0, kr1, vr0, vr1;
    {
      const u16* kp = Kb + qkbase + (size_t)vrow * DIM + scol;
      kr0 = *(const u16x8*)kp; kr1 = *(const u16x8*)(kp + 8);
      const u16* vp = Vtg + vbase + (size_t)vrow * SEQ + scol;
      vr0 = *(const u16x8*)vp; vr1 = *(const u16x8*)(vp + 8);
    }

    float mrun[2] = {-1e30f, -1e30f}, lrun[2] = {0.f, 0.f};
    v4f O[4][2];
    #pragma unroll
    for (int di = 0; di < 4; di++)
      #pragma unroll
      for (int ni = 0; ni < 2; ni++) O[di][ni] = (v4f){0.f, 0.f, 0.f, 0.f};

    for (int it = 0; it < ntiles; ++it) {
      const int kv0 = it * KT;
      __syncthreads();  // all waves done reading previous tile
      *(u16x8*)(Ks + krow * PAD + scol) = kr0;
      *(u16x8*)(Ks + krow * PAD + scol + 8) = kr1;
      *(u16x8*)(Vs + vrow * PAD + scol) = vr0;
      *(u16x8*)(Vs + vrow * PAD + scol + 8) = vr1;
      __syncthreads();
      // prefetch next tile (consumed after next barrier -> latency hidden)
      if (it + 1 < ntiles) {
        const int nkv = kv0 + KT;
        const u16* kp = Kb + qkbase + (size_t)(nkv + vrow) * DIM + scol;
        kr0 = *(const u16x8*)kp; kr1 = *(const u16x8*)(kp + 8);
        const u16* vp = Vtg + vbase + (size_t)vrow * SEQ + nkv + scol;
        vr0 = *(const u16x8*)vp; vr1 = *(const u16x8*)(vp + 8);
      }
      if (kv0 > wq + 31) continue;  // tile fully masked for this wave

      // ---- S^T = K*Q^T : sc[mi][ni], rows kv (permuted), cols q ----
      v4f sc[4][2];
      #pragma unroll
      for (int mi = 0; mi < 4; mi++)
        #pragma unroll
        for (int ni = 0; ni < 2; ni++) sc[mi][ni] = (v4f){0.f, 0.f, 0.f, 0.f};
      #pragma unroll
      for (int kc = 0; kc < 2; kc++) {
        #pragma unroll
        for (int mi = 0; mi < 4; mi++) {
          s8v kf = *(const s8v*)(Ks + (mi * 16 + l16) * PAD + kc * 32 + quad * 8);
          sc[mi][0] = __builtin_amdgcn_mfma_f32_16x16x32_bf16(kf, qf[0][kc], sc[mi][0], 0, 0, 0);
          sc[mi][1] = __builtin_amdgcn_mfma_f32_16x16x32_bf16(kf, qf[1][kc], sc[mi][1], 0, 0, 0);
        }
      }

      // ---- causal mask: kv_g = kv0 + pi(mi,quad,r), q_g = wq + ni*16 + l16 ----
      if (kv0 + KT > wq) {
        #pragma unroll
        for (int mi = 0; mi < 4; mi++) {
          const int kvb = kv0 + (mi & 1) * 32 + quad * 8 + (mi >> 1) * 4;
          #pragma unroll
          for (int ni = 0; ni < 2; ni++) {
            const int qg = wq + ni * 16 + l16;
            #pragma unroll
            for (int r = 0; r < 4; r++)
              if (kvb + r > qg) sc[mi][ni][r] = -1e30f;
          }
        }
      }

      // ---- online softmax: per lane 16 kv values, 2 shuffles per reduce ----
      float alpha[2];
      #pragma unroll
      for (int ni = 0; ni < 2; ni++) {
        float mx = -1e30f;
        #pragma unroll
        for (int mi = 0; mi < 4; mi++)
          #pragma unroll
          for (int r = 0; r < 4; r++) mx = fmaxf(mx, sc[mi][ni][r]);
        mx = fmaxf(mx, __shfl_xor(mx, 16, 64));
        mx = fmaxf(mx, __shfl_xor(mx, 32, 64));
        const float mnew = fmaxf(mrun[ni], mx);
        alpha[ni] = fast_exp2(mrun[ni] - mnew);
        mrun[ni] = mnew;
        float rsum = 0.f;
        #pragma unroll
        for (int mi = 0; mi < 4; mi++)
          #pragma unroll
          for (int r = 0; r < 4; r++) {
            float p = fast_exp2(sc[mi][ni][r] - mnew);
            sc[mi][ni][r] = p;
            rsum += p;
          }
        rsum += __shfl_xor(rsum, 16, 64);
        rsum += __shfl_xor(rsum, 32, 64);
        lrun[ni] = lrun[ni] * alpha[ni] + rsum;
      }
      #pragma unroll
      for (int di = 0; di < 4; di++)
        #pragma unroll
        for (int ni = 0; ni < 2; ni++)
          #pragma unroll
          for (int r = 0; r < 4; r++) O[di][ni][r] *= alpha[ni];

      // ---- pack P^T as PV B-frag: pf[ni][kc][j] = P[q][kv=kc*32+quad*8+j] ----
      s8v pf[2][2];
      #pragma unroll
      for (int ni = 0; ni < 2; ni++)
        #pragma unroll
        for (int kc = 0; kc < 2; kc++)
          #pragma unroll
          for (int j = 0; j < 8; j++)
            pf[ni][kc][j] = (short)f2bf(sc[kc + 2 * (j >> 2)][ni][j & 3]);

      // ---- PV: O^T[d][q] += Vt * P^T ----
      #pragma unroll
      for (int kc = 0; kc < 2; kc++) {
        #pragma unroll
        for (int di = 0; di < 4; di++) {
          s8v vf = *(const s8v*)(Vs + (di * 16 + l16) * PAD + kc * 32 + quad * 8);
          O[di][0] = __builtin_amdgcn_mfma_f32_16x16x32_bf16(vf, pf[0][kc], O[di][0], 0, 0, 0);
          O[di][1] = __builtin_amdgcn_mfma_f32_16x16x32_bf16(vf, pf[1][kc], O[di][1], 0, 0, 0);
        }
      }
    }

    // ---- epilogue: normalize, transpose via LDS (wave-private rows), coalesced write ----
    const float inv0 = 1.f / lrun[0], inv1 = 1.f / lrun[1];
    #pragma unroll
    for (int di = 0; di < 4; di++)
      #pragma unroll
      for (int ni = 0; ni < 2; ni++) {
        const float inv = ni ? inv1 : inv0;
        #pragma unroll
        for (int r = 0; r < 4; r++)
          QPs[(w * 32 + ni * 16 + l16) * PAD + di * 16 + quad * 4 + r] = f2bf(O[di][ni][r] * inv);
      }
    __syncthreads();
    {
      const int r = t >> 1, c0 = (t & 1) * 32;
      u16* dst = Ob + qkbase + (size_t)(q0 + r) * DIM + c0;
      #pragma unroll
      for (int ch = 0; ch < 4; ch++)
        *(u16x8*)(dst + ch * 8) = *(const u16x8*)(QPs + r * PAD + c0 + ch * 8);
    }
  }
}

// ---------------- launch ----------------
extern "C" void kernel_launch(void* const* d_in, const int* in_sizes, int n_in,
                              void* d_out, int out_size, void* d_ws, size_t ws_size,
                              hipStream_t stream) {
  (void)in_sizes; (void)n_in; (void)out_size; (void)ws_size;
  const float* x  = (const float*)d_in[0];
  const float* Wq = (const float*)d_in[1];
  const float* Wk = (const float*)d_in[2];
  const float* Wv = (const float*)d_in[3];
  const float* Wo = (const float*)d_in[4];
  const float* bo = (const float*)d_in[5];
  float* out = (float*)d_out;

  char* ws = (char*)d_ws;
  const size_t MB = 1024ull * 1024ull;
  u16* Xb  = (u16*)(ws);             // 16 MB: x bf16 [8192][1024]
  u16* Wt  = (u16*)(ws + 16 * MB);   //  8 MB: Wq,Wk,Wv,Wo transposed bf16
  u16* Qb  = (u16*)(ws + 24 * MB);   // 16 MB
  u16* Kb  = (u16*)(ws + 40 * MB);   // 16 MB
  u16* Vtg = (u16*)(ws + 56 * MB);   // 16 MB: V transposed [b][h][d][s]
  u16* Cb  = (u16*)(ws + 72 * MB);   // 16 MB: ctx -> 88 MB total

  const int NTOK = BSZ * SEQ;  // 8192
  const int n4 = NTOK * DIM / 4;
  cast_bf16_kernel<<<(n4 + 255) / 256, 256, 0, stream>>>(x, Xb, n4);
  transpose_cast_kernel<<<dim3(32, 32, 4), 256, 0, stream>>>(Wq, Wk, Wv, Wo, Wt);

  gemm_qkv<<<dim3(DIM / 128, NTOK / 128, 3), 256, 0, stream>>>(Xb, Wt, Qb, Kb, Vtg);

  flash_attn_mfma<<<dim3(SEQ / QT / 2, NH, BSZ), 256, 0, stream>>>(Qb, Kb, Vtg, Cb);

  gemm_proj<<<dim3(DIM / 128, NTOK / 128), 256, 0, stream>>>(Cb, Wt + 3ull * DIM * DIM, out, bo);
}

// Round 4
// 311.858 us; speedup vs baseline: 7.9942x; 1.0154x over previous
//
#include <hip/hip_runtime.h>

// ---- problem constants ----
#define BSZ 4
#define SEQ 2048
#define DIM 1024
#define NH  16
#define HD  64
#define QT  128   // q rows per block pass (flash)
#define KT  64    // kv rows per tile (flash)
#define PAD 72    // u16 row stride in flash LDS

typedef float v4f __attribute__((ext_vector_type(4)));
typedef short s8v __attribute__((ext_vector_type(8)));
typedef unsigned short u16;
typedef unsigned short u16x8 __attribute__((ext_vector_type(8)));
typedef unsigned short u16x4 __attribute__((ext_vector_type(4)));

__device__ __forceinline__ u16 f2bf(float f) {
  unsigned int u = __builtin_bit_cast(unsigned int, f);
  unsigned int r = u + 0x7fffu + ((u >> 16) & 1u);  // RNE
  return (u16)(r >> 16);
}
__device__ __forceinline__ float bf2f(u16 h) {
  return __builtin_bit_cast(float, (unsigned int)h << 16);
}
__device__ __forceinline__ float fast_exp2(float x) {
#if __has_builtin(__builtin_amdgcn_exp2f)
  return __builtin_amdgcn_exp2f(x);
#else
  return exp2f(x);
#endif
}
// async global->LDS, 16B per lane; lds ptr must be wave-uniform (HW adds lane*16)
__device__ __forceinline__ void gll16(const u16* g, u16* l) {
  __builtin_amdgcn_global_load_lds((const __attribute__((address_space(1))) void*)g,
                                   (__attribute__((address_space(3))) void*)l, 16, 0, 0);
}

// ---------------- cast x (fp32) -> bf16 ----------------
__global__ __launch_bounds__(256) void cast_bf16_kernel(const float* __restrict__ x,
                                                        u16* __restrict__ o, int n4) {
  int i = blockIdx.x * 256 + threadIdx.x;
  if (i >= n4) return;
  v4f v = reinterpret_cast<const v4f*>(x)[i];
  u16x4 r;
  #pragma unroll
  for (int c = 0; c < 4; c++) r[c] = f2bf(v[c]);
  reinterpret_cast<u16x4*>(o)[i] = r;
}

// ---------------- transpose + cast W[k][n] -> Wt[n][k] bf16 ----------------
__global__ __launch_bounds__(256) void transpose_cast_kernel(const float* __restrict__ W0,
                                                             const float* __restrict__ W1,
                                                             const float* __restrict__ W2,
                                                             const float* __restrict__ W3,
                                                             u16* __restrict__ out) {
  const float* W = blockIdx.z == 0 ? W0 : blockIdx.z == 1 ? W1 : blockIdx.z == 2 ? W2 : W3;
  u16* T = out + (size_t)blockIdx.z * DIM * DIM;
  __shared__ float tile[32][33];
  int tx = threadIdx.x & 31, ty = threadIdx.x >> 5;
  int bn = blockIdx.x * 32, bk = blockIdx.y * 32;
  #pragma unroll
  for (int r = 0; r < 4; r++) {
    int k = bk + ty + r * 8;
    tile[ty + r * 8][tx] = W[(size_t)k * DIM + bn + tx];
  }
  __syncthreads();
  #pragma unroll
  for (int r = 0; r < 4; r++) {
    int n = bn + ty + r * 8;
    T[(size_t)n * DIM + bk + tx] = f2bf(tile[tx][ty + r * 8]);
  }
}

// ======== shared GEMM core (128x128 tile, BK=64, async staging, XCD-swizzled) ========
// LDS per 32-k half (16B chunks): chunk = (m>>4)*64 + kk*16 + (m&15); halves stacked
// at +4096 u16. Staging per half: wave w, inst p: lane L -> row (w*2+p)*16+(L&15),
// k-chunk L>>4; LDS chunk (w*2+p)*64 + L (contiguous in lane order -> global_load_lds OK).
// XCD swizzle: flat = x + 8y; xcd = flat&7 owns m-panels [xcd*8, xcd*8+8) x all n
// -> per-XCD L2 working set = 2MB A-slab + 2MB W  (L2 = 4MB).

#define GEMM_PROLOGUE()                                                          \
  const int flat = blockIdx.x + 8 * blockIdx.y;                                  \
  const int xcd = flat & 7, slot = flat >> 3;                                    \
  const int m0 = (xcd * 8 + (slot & 7)) * 128;                                   \
  const int n0 = (slot >> 3) * 128;                                              \
  const int t = threadIdx.x;                                                     \
  const int lane = t & 63, w = t >> 6;                                           \
  const int waveM = w >> 1, waveN = w & 1;                                       \
  const int quad = lane >> 4, l16 = lane & 15;                                   \
  __shared__ u16 Al[8192];                                                       \
  __shared__ u16 Bl[8192];                                                       \
  v4f acc[4][4];                                                                 \
  _Pragma("unroll") for (int i = 0; i < 4; i++)                                  \
    _Pragma("unroll") for (int j = 0; j < 4; j++)                                \
      acc[i][j] = (v4f){0.f, 0.f, 0.f, 0.f};                                     \
  const int sR = lane & 15, sC = lane >> 4;                                      \
  const u16* Ag0 = A  + (size_t)(m0 + (w * 2 + 0) * 16 + sR) * DIM + sC * 8;     \
  const u16* Ag1 = A  + (size_t)(m0 + (w * 2 + 1) * 16 + sR) * DIM + sC * 8;     \
  const u16* Bg0 = Bt + (size_t)(n0 + (w * 2 + 0) * 16 + sR) * DIM + sC * 8;     \
  const u16* Bg1 = Bt + (size_t)(n0 + (w * 2 + 1) * 16 + sR) * DIM + sC * 8;     \
  u16* Al0 = Al + (w * 2 + 0) * 512;                                             \
  u16* Al1 = Al + (w * 2 + 1) * 512;                                             \
  u16* Bl0 = Bl + (w * 2 + 0) * 512;                                             \
  u16* Bl1 = Bl + (w * 2 + 1) * 512;                                             \
  const int abase = waveM * 2048 + quad * 128 + l16 * 8;                         \
  const int bbase = waveN * 2048 + quad * 128 + l16 * 8;                         \
  for (int k0 = 0; k0 < DIM; k0 += 64) {                                         \
    __syncthreads();                                                             \
    gll16(Ag0 + k0, Al0);        gll16(Ag1 + k0, Al1);                           \
    gll16(Bg0 + k0, Bl0);        gll16(Bg1 + k0, Bl1);                           \
    gll16(Ag0 + k0 + 32, Al0 + 4096); gll16(Ag1 + k0 + 32, Al1 + 4096);          \
    gll16(Bg0 + k0 + 32, Bl0 + 4096); gll16(Bg1 + k0 + 32, Bl1 + 4096);          \
    __syncthreads();                                                             \
    _Pragma("unroll") for (int hh = 0; hh < 2; hh++) {                           \
      s8v af[4], bfv[4];                                                         \
      _Pragma("unroll") for (int i = 0; i < 4; i++)                              \
        af[i] = *(const s8v*)(Al + hh * 4096 + abase + i * 512);                 \
      _Pragma("unroll") for (int j = 0; j < 4; j++)                              \
        bfv[j] = *(const s8v*)(Bl + hh * 4096 + bbase + j * 512);                \
      _Pragma("unroll") for (int i = 0; i < 4; i++)                              \
        _Pragma("unroll") for (int j = 0; j < 4; j++)                            \
          acc[i][j] = __builtin_amdgcn_mfma_f32_16x16x32_bf16(af[i], bfv[j],     \
                                                              acc[i][j], 0, 0, 0);\
    }                                                                            \
  }

// ---------------- fused QKV GEMM; z=0 -> Q, z=1 -> K, z=2 -> V written transposed ----------------
__global__ __launch_bounds__(256, 4) void gemm_qkv(const u16* __restrict__ A, const u16* __restrict__ Wt,
                                                   u16* __restrict__ Qb, u16* __restrict__ Kb,
                                                   u16* __restrict__ Vtg) {
  const int z = blockIdx.z;
  const u16* Bt = Wt + (size_t)z * DIM * DIM;
  GEMM_PROLOGUE()
  if (z == 2) {
    // write V transposed: Vtg[((b*NH+h)*HD+d)*SEQ + s]
    #pragma unroll
    for (int i = 0; i < 4; i++) {
      #pragma unroll
      for (int j = 0; j < 4; j++) {
        int gm0 = m0 + waveM * 64 + i * 16 + quad * 4;
        int gn = n0 + waveN * 64 + j * 16 + l16;
        int b = gm0 >> 11, s0 = gm0 & (SEQ - 1), hh2 = gn >> 6, d = gn & (HD - 1);
        u16x4 o;
        #pragma unroll
        for (int r = 0; r < 4; r++) o[r] = f2bf(acc[i][j][r]);
        *(u16x4*)(Vtg + ((size_t)(b * NH + hh2) * HD + d) * SEQ + s0) = o;
      }
    }
  } else {
    u16* C = (z == 0) ? Qb : Kb;
    #pragma unroll
    for (int i = 0; i < 4; i++) {
      #pragma unroll
      for (int j = 0; j < 4; j++) {
        int gn = n0 + waveN * 64 + j * 16 + l16;
        #pragma unroll
        for (int r = 0; r < 4; r++) {
          int gm = m0 + waveM * 64 + i * 16 + quad * 4 + r;
          C[(size_t)gm * DIM + gn] = f2bf(acc[i][j][r]);
        }
      }
    }
  }
}

// ---------------- projection GEMM: out = ctx * Wo^T + bias (fp32 out) ----------------
__global__ __launch_bounds__(256, 4) void gemm_proj(const u16* __restrict__ A, const u16* __restrict__ Bt,
                                                    float* __restrict__ Cf, const float* __restrict__ bias) {
  GEMM_PROLOGUE()
  #pragma unroll
  for (int i = 0; i < 4; i++) {
    #pragma unroll
    for (int j = 0; j < 4; j++) {
      int gn = n0 + waveN * 64 + j * 16 + l16;
      float bv = bias[gn];
      #pragma unroll
      for (int r = 0; r < 4; r++) {
        int gm = m0 + waveM * 64 + i * 16 + quad * 4 + r;
        Cf[(size_t)gm * DIM + gn] = acc[i][j][r] + bv;
      }
    }
  }
}

// ---------------- MFMA flash attention (causal), transposed scores ----------------
// S^T = K*Q^T (K rows permuted so P^T registers are directly the PV B-fragment).
// Softmax over kv: 16 in-register values + 2 shfl_xor. O^T = Vt*P^T in C-layout.
// Causal balance: block pair {px, 15-px} -> 34 KV-tiles each. Grid (NH, px, BSZ):
// id%8 = h%8 -> both q-pass blocks of a head share an XCD (KV L2 locality:
// 2 heads x 4 batches x 512KB = 4MB/XCD).
__global__ __launch_bounds__(256, 3) void flash_attn_mfma(const u16* __restrict__ Qb,
                                                          const u16* __restrict__ Kb,
                                                          const u16* __restrict__ Vtg,
                                                          u16* __restrict__ Ob) {
  const int h = blockIdx.x, px = blockIdx.y, bb = blockIdx.z;
  const int t = threadIdx.x;
  const int lane = t & 63, w = t >> 6;
  const int quad = lane >> 4, l16 = lane & 15;

  __shared__ u16 QPs[QT * PAD];  // Q staging, then O^T epilogue bounce
  __shared__ u16 Ks[KT * PAD];   // K tile, rows permuted by pi^-1
  __shared__ u16 Vs[HD * PAD];   // V tile, [d][kv]

  const size_t qkbase = (size_t)bb * SEQ * DIM + h * HD;
  const size_t vbase = ((size_t)bb * NH + h) * (size_t)HD * SEQ;

  const int vrow = t >> 2, scol = (t & 3) * 16;
  const int krow = ((vrow >> 5) + 2 * ((vrow >> 2) & 1)) * 16 + ((vrow >> 3) & 3) * 4 + (vrow & 3);

  for (int pass = 0; pass < 2; pass++) {
    const int qi = (pass == 0) ? px : (SEQ / QT - 1 - px);
    const int q0 = qi * QT;
    const int wq = q0 + w * 32;
    const int ntiles = 2 * qi + 2;

    __syncthreads();  // QPs free (previous pass epilogue complete)

    // stage Q scaled by 1/sqrt(HD) * log2(e)  (softmax in exp2 domain)
    {
      const int r = t >> 1, c0 = (t & 1) * 32;
      const u16* src = Qb + qkbase + (size_t)(q0 + r) * DIM + c0;
      const float scq = 0.18033688011112042f;
      #pragma unroll
      for (int ch = 0; ch < 4; ch++) {
        u16x8 u = *(const u16x8*)(src + ch * 8);
        u16x8 o;
        #pragma unroll
        for (int j = 0; j < 8; j++) o[j] = f2bf(bf2f(u[j]) * scq);
        *(u16x8*)(QPs + r * PAD + c0 + ch * 8) = o;
      }
    }
    __syncthreads();

    // Q B-fragments: B[n=q][k=d]
    s8v qf[2][2];
    #pragma unroll
    for (int ni = 0; ni < 2; ni++)
      #pragma unroll
      for (int kc = 0; kc < 2; kc++)
        qf[ni][kc] = *(const s8v*)(QPs + (w * 32 + ni * 16 + l16) * PAD + kc * 32 + quad * 8);

    // preload KV tile 0 into registers
    u16x8 kr0, kr1, vr0, vr1;
    {
      const u16* kp = Kb + qkbase + (size_t)vrow * DIM + scol;
      kr0 = *(const u16x8*)kp; kr1 = *(const u16x8*)(kp + 8);
      const u16* vp = Vtg + vbase + (size_t)vrow * SEQ + scol;
      vr0 = *(const u16x8*)vp; vr1 = *(const u16x8*)(vp + 8);
    }

    float mrun[2] = {-1e30f, -1e30f}, lrun[2] = {0.f, 0.f};
    v4f O[4][2];
    #pragma unroll
    for (int di = 0; di < 4; di++)
      #pragma unroll
      for (int ni = 0; ni < 2; ni++) O[di][ni] = (v4f){0.f, 0.f, 0.f, 0.f};

    for (int it = 0; it < ntiles; ++it) {
      const int kv0 = it * KT;
      __syncthreads();
      *(u16x8*)(Ks + krow * PAD + scol) = kr0;
      *(u16x8*)(Ks + krow * PAD + scol + 8) = kr1;
      *(u16x8*)(Vs + vrow * PAD + scol) = vr0;
      *(u16x8*)(Vs + vrow * PAD + scol + 8) = vr1;
      __syncthreads();
      if (it + 1 < ntiles) {  // prefetch next tile (consumed after next barrier)
        const int nkv = kv0 + KT;
        const u16* kp = Kb + qkbase + (size_t)(nkv + vrow) * DIM + scol;
        kr0 = *(const u16x8*)kp; kr1 = *(const u16x8*)(kp + 8);
        const u16* vp = Vtg + vbase + (size_t)vrow * SEQ + nkv + scol;
        vr0 = *(const u16x8*)vp; vr1 = *(const u16x8*)(vp + 8);
      }
      if (kv0 > wq + 31) continue;  // tile fully masked for this wave

      // ---- S^T = K*Q^T : sc[mi][ni], rows kv (permuted), cols q ----
      v4f sc[4][2];
      #pragma unroll
      for (int mi = 0; mi < 4; mi++)
        #pragma unroll
        for (int ni = 0; ni < 2; ni++) sc[mi][ni] = (v4f){0.f, 0.f, 0.f, 0.f};
      #pragma unroll
      for (int kc = 0; kc < 2; kc++) {
        #pragma unroll
        for (int mi = 0; mi < 4; mi++) {
          s8v kf = *(const s8v*)(Ks + (mi * 16 + l16) * PAD + kc * 32 + quad * 8);
          sc[mi][0] = __builtin_amdgcn_mfma_f32_16x16x32_bf16(kf, qf[0][kc], sc[mi][0], 0, 0, 0);
          sc[mi][1] = __builtin_amdgcn_mfma_f32_16x16x32_bf16(kf, qf[1][kc], sc[mi][1], 0, 0, 0);
        }
      }

      // ---- causal mask: kv_g = kv0 + pi(mi,quad,r), q_g = wq + ni*16 + l16 ----
      if (kv0 + KT > wq) {
        #pragma unroll
        for (int mi = 0; mi < 4; mi++) {
          const int kvb = kv0 + (mi & 1) * 32 + quad * 8 + (mi >> 1) * 4;
          #pragma unroll
          for (int ni = 0; ni < 2; ni++) {
            const int qg = wq + ni * 16 + l16;
            #pragma unroll
            for (int r = 0; r < 4; r++)
              if (kvb + r > qg) sc[mi][ni][r] = -1e30f;
          }
        }
      }

      // ---- online softmax: per lane 16 kv values, 2 shuffles per reduce ----
      float alpha[2];
      #pragma unroll
      for (int ni = 0; ni < 2; ni++) {
        float mx = -1e30f;
        #pragma unroll
        for (int mi = 0; mi < 4; mi++)
          #pragma unroll
          for (int r = 0; r < 4; r++) mx = fmaxf(mx, sc[mi][ni][r]);
        mx = fmaxf(mx, __shfl_xor(mx, 16, 64));
        mx = fmaxf(mx, __shfl_xor(mx, 32, 64));
        const float mnew = fmaxf(mrun[ni], mx);
        alpha[ni] = fast_exp2(mrun[ni] - mnew);
        mrun[ni] = mnew;
        float rsum = 0.f;
        #pragma unroll
        for (int mi = 0; mi < 4; mi++)
          #pragma unroll
          for (int r = 0; r < 4; r++) {
            float p = fast_exp2(sc[mi][ni][r] - mnew);
            sc[mi][ni][r] = p;
            rsum += p;
          }
        rsum += __shfl_xor(rsum, 16, 64);
        rsum += __shfl_xor(rsum, 32, 64);
        lrun[ni] = lrun[ni] * alpha[ni] + rsum;
      }
      #pragma unroll
      for (int di = 0; di < 4; di++)
        #pragma unroll
        for (int ni = 0; ni < 2; ni++)
          #pragma unroll
          for (int r = 0; r < 4; r++) O[di][ni][r] *= alpha[ni];

      // ---- pack P^T as PV B-frag: pf[ni][kc][j] = P[q][kv=kc*32+quad*8+j] ----
      s8v pf[2][2];
      #pragma unroll
      for (int ni = 0; ni < 2; ni++)
        #pragma unroll
        for (int kc = 0; kc < 2; kc++)
          #pragma unroll
          for (int j = 0; j < 8; j++)
            pf[ni][kc][j] = (short)f2bf(sc[kc + 2 * (j >> 2)][ni][j & 3]);

      // ---- PV: O^T[d][q] += Vt * P^T ----
      #pragma unroll
      for (int kc = 0; kc < 2; kc++) {
        #pragma unroll
        for (int di = 0; di < 4; di++) {
          s8v vf = *(const s8v*)(Vs + (di * 16 + l16) * PAD + kc * 32 + quad * 8);
          O[di][0] = __builtin_amdgcn_mfma_f32_16x16x32_bf16(vf, pf[0][kc], O[di][0], 0, 0, 0);
          O[di][1] = __builtin_amdgcn_mfma_f32_16x16x32_bf16(vf, pf[1][kc], O[di][1], 0, 0, 0);
        }
      }
    }

    // ---- epilogue: normalize, transpose via LDS (wave-private rows), coalesced write ----
    const float inv0 = 1.f / lrun[0], inv1 = 1.f / lrun[1];
    #pragma unroll
    for (int di = 0; di < 4; di++)
      #pragma unroll
      for (int ni = 0; ni < 2; ni++) {
        const float inv = ni ? inv1 : inv0;
        #pragma unroll
        for (int r = 0; r < 4; r++)
          QPs[(w * 32 + ni * 16 + l16) * PAD + di * 16 + quad * 4 + r] = f2bf(O[di][ni][r] * inv);
      }
    __syncthreads();
    {
      const int r = t >> 1, c0 = (t & 1) * 32;
      u16* dst = Ob + qkbase + (size_t)(q0 + r) * DIM + c0;
      #pragma unroll
      for (int ch = 0; ch < 4; ch++)
        *(u16x8*)(dst + ch * 8) = *(const u16x8*)(QPs + r * PAD + c0 + ch * 8);
    }
  }
}

// ---------------- launch ----------------
extern "C" void kernel_launch(void* const* d_in, const int* in_sizes, int n_in,
                              void* d_out, int out_size, void* d_ws, size_t ws_size,
                              hipStream_t stream) {
  (void)in_sizes; (void)n_in; (void)out_size; (void)ws_size;
  const float* x  = (const float*)d_in[0];
  const float* Wq = (const float*)d_in[1];
  const float* Wk = (const float*)d_in[2];
  const float* Wv = (const float*)d_in[3];
  const float* Wo = (const float*)d_in[4];
  const float* bo = (const float*)d_in[5];
  float* out = (float*)d_out;

  char* ws = (char*)d_ws;
  const size_t MB = 1024ull * 1024ull;
  u16* Xb  = (u16*)(ws);             // 16 MB: x bf16 [8192][1024]
  u16* Wt  = (u16*)(ws + 16 * MB);   //  8 MB: Wq,Wk,Wv,Wo transposed bf16
  u16* Qb  = (u16*)(ws + 24 * MB);   // 16 MB
  u16* Kb  = (u16*)(ws + 40 * MB);   // 16 MB
  u16* Vtg = (u16*)(ws + 56 * MB);   // 16 MB: V transposed [b][h][d][s]
  u16* Cb  = (u16*)(ws + 72 * MB);   // 16 MB: ctx -> 88 MB total

  const int NTOK = BSZ * SEQ;  // 8192
  const int n4 = NTOK * DIM / 4;
  cast_bf16_kernel<<<(n4 + 255) / 256, 256, 0, stream>>>(x, Xb, n4);
  transpose_cast_kernel<<<dim3(32, 32, 4), 256, 0, stream>>>(Wq, Wk, Wv, Wo, Wt);

  gemm_qkv<<<dim3(DIM / 128, NTOK / 128, 3), 256, 0, stream>>>(Xb, Wt, Qb, Kb, Vtg);

  flash_attn_mfma<<<dim3(NH, SEQ / QT / 2, BSZ), 256, 0, stream>>>(Qb, Kb, Vtg, Cb);

  gemm_proj<<<dim3(DIM / 128, NTOK / 128), 256, 0, stream>>>(Cb, Wt + 3ull * DIM * DIM, out, bo);
}